// Round 4
// baseline (497.805 us; speedup 1.0000x reference)
//
#include <hip/hip_runtime.h>

typedef int v4i __attribute__((ext_vector_type(4)));

#define QMAX 127.0f

// ---- workspace layout ----
// xq  : int8 padded, swizzled [16][66][66 px][5 c5][4 slots][16]
//       slot s of (col,c5) holds logical ci-chunk s ^ ((col>>1)&3)
// wq2 : int8 fragment-order [9][5][20cog][64lane][16]
// bi  : float [320]
#define XQ_BYTES 22302720
#define WQ_BYTES 921600

__device__ __forceinline__ float clampf(float v, float lo, float hi) {
    return fminf(fmaxf(v, lo), hi);
}

__device__ __forceinline__ void gload_lds16(const char* g, char* l) {
    __builtin_amdgcn_global_load_lds(
        (const __attribute__((address_space(1))) void*)g,
        (__attribute__((address_space(3))) void*)l, 16, 0, 0);
}

__device__ __forceinline__ v4i mfma_i8(v4i a, v4i b, v4i c) {
    return __builtin_amdgcn_mfma_i32_16x16x64_i8(a, b, c, 0, 0, 0);
}

// ---------------------------------------------------------------------------
// x (NCHW f32) -> quantize -> xq interior. One block per (h,b): writes the
// full contiguous 20,480B span of row h+1 (no cross-block line sharing).
// 5 passes of 64 ci through an LDS transpose; packed output held in VGPRs.
// ---------------------------------------------------------------------------
__global__ __launch_bounds__(256) void quant_x_kernel(
    const float* __restrict__ x, const float* __restrict__ step_p,
    char* __restrict__ xq)
{
    __shared__ float F[64 * 65];   // [ci_local][w], stride 65 floats
    const int t = threadIdx.x;
    const int h = blockIdx.x;
    const int b = blockIdx.y;
    const float step = *step_p;
    const int w  = t >> 2;         // output col-1 (0..63)
    const int cg = t & 3;          // logical 16-ci chunk within c5
    v4i vals[5];

    for (int c5 = 0; c5 < 5; ++c5) {
        // phase 1: 64 ci-rows x 64 w; wave-instr = 4 contiguous 256B rows
        {
            const int r = t >> 4, c = (t & 15) * 4;
            const float* src = x + (((size_t)(b * 320 + c5 * 64) * 64 + h) * 64);
#pragma unroll
            for (int i = 0; i < 4; ++i) {
                const int row = r + i * 16;
                *(float4*)&F[row * 65 + c] =
                    *(const float4*)(src + (size_t)row * 4096 + c);
            }
        }
        __syncthreads();
        // phase 2: pack 16 ci bytes for pixel col w+1
        int dws[4];
#pragma unroll
        for (int j = 0; j < 4; ++j) {
            int word = 0;
#pragma unroll
            for (int k = 0; k < 4; ++k) {
                float v = F[(cg * 16 + j * 4 + k) * 65 + w];
                int xi = (int)clampf(rintf(v / step), -QMAX, QMAX);
                word |= (xi & 0xFF) << (8 * k);
            }
            dws[j] = word;
        }
        vals[c5] = (v4i){dws[0], dws[1], dws[2], dws[3]};
        __syncthreads();
    }

    // store: full 320B ci-vector of (b, h+1, w+1); swizzled chunk slot
    const int col = w + 1;
    const int key = (col >> 1) & 3;
    char* base = xq + ((size_t)(b * 66 + (h + 1)) * 66 + col) * 320;
#pragma unroll
    for (int c5 = 0; c5 < 5; ++c5)
        *(v4i*)(base + c5 * 64 + (((cg ^ key)) << 4)) = vals[c5];
}

// ---------------------------------------------------------------------------
// Fused prep: [0,3600) wq2 quantize (coalesced writes), [3600,3925) halo zero
// (zeros are swizzle-invariant), [3925] bias constant.
// ---------------------------------------------------------------------------
__global__ __launch_bounds__(256) void prep_kernel(
    const float* __restrict__ w, const float* __restrict__ bias,
    const float* __restrict__ step_w_p, const float* __restrict__ step_b_p,
    const float* __restrict__ step_x_p, const float* __restrict__ shift_p,
    char* __restrict__ wq2, char* __restrict__ xq, float* __restrict__ bi)
{
    const int bid = blockIdx.x;
    if (bid < 3600) {
        const int tid = bid * 256 + threadIdx.x;
        const float step = *step_w_p;
        const int p    = tid / 102400;
        const int r    = tid - p * 102400;
        const int c5   = r / 20480;
        const int r2   = r - c5 * 20480;
        const int cog  = r2 >> 10;
        const int r3   = r2 & 1023;
        const int lane = r3 >> 4, j = r3 & 15;
        const int co = cog * 16 + (lane & 15);
        const int ci = c5 * 64 + (lane >> 4) * 16 + j;
        float v = w[(size_t)co * 2880 + ci * 9 + p];
        int q = (int)clampf(rintf(v / step), -QMAX, QMAX);
        wq2[tid] = (char)q;
    } else if (bid < 3925) {
        int tid = (bid - 3600) * 256 + threadIdx.x;
        if (tid < 83200) {
            int b = tid / 5200;
            int r = tid - b * 5200;
            int px = r / 20;
            int ck = (r - px * 20) * 16;
            int row, col;
            if (px < 66)       { row = 0;  col = px; }
            else if (px < 132) { row = 65; col = px - 66; }
            else { int e = px - 132; row = 1 + (e >> 1); col = (e & 1) * 65; }
            size_t off = ((size_t)(b * 66 + row) * 66 + col) * 320 + ck;
            v4i z = {0, 0, 0, 0};
            *(v4i*)&xq[off] = z;
        }
    } else {
        const float step_b = *step_b_p;
        const float xs = 1.0f / *step_x_p;
        const float ws = 1.0f / *step_w_p;
        const float shift = *shift_p;
#pragma unroll
        for (int co = threadIdx.x; co < 320; co += 256) {
            float b_deq = clampf(rintf(bias[co] / step_b), -QMAX, QMAX) * step_b;
            float v = ((b_deq * shift) * xs) * ws;
            bi[co] = clampf(rintf(v), -QMAX, QMAX);
        }
    }
}

// ---------------------------------------------------------------------------
// Implicit-GEMM conv, v_mfma_i32_16x16x64_i8.
// LDS = B only (42,240 B) -> 3 blocks/CU. B staged by global_load_lds DMA
// (xq pre-swizzled in global). A-fragments read directly from L2-hot wq2
// (1KB coalesced per wave-instr, no LDS, no barrier dependency).
// Wave tile 64co x 128px (2 output rows); block = 4 waves = 8 rows.
// ---------------------------------------------------------------------------
__global__ __launch_bounds__(256, 3) void conv_mfma_kernel(
    const char* __restrict__ xq, const char* __restrict__ wq2,
    const float* __restrict__ bi, const float* __restrict__ shift_p,
    float* __restrict__ out)
{
    __shared__ __attribute__((aligned(16))) char B_lds[42240]; // 10 rows x 66 x 64

    const int t   = threadIdx.x;
    const int bx  = blockIdx.x;          // co tile 0..4
    const int co0 = bx * 64;
    const int ptile = blockIdx.y;        // 0..127
    const int b  = ptile >> 3;
    const int h0 = (ptile & 7) * 8;

    const int wave = t >> 6, lane = t & 63;
    const int quad = lane >> 4, l15 = lane & 15;

    const char* xbase = xq + ((size_t)(b * 66 + h0) * 66) * 320;

    v4i acc[4][8] = {};

    for (int c5 = 0; c5 < 5; ++c5) {
        const int ci0 = c5 * 64;
        const char* wp = wq2 + (c5 * 20 + bx * 4) * 1024 + lane * 16;

        // --- stage B: 2640 16B chunks via LDS-DMA (global already swizzled)
        for (int c = t; c < 2640; c += 256) {
            const char* g = xbase + (c >> 2) * 320 + ci0 + ((c & 3) << 4);
            gload_lds16(g, &B_lds[(c - lane) * 16]);
        }
        __syncthreads();

#pragma unroll
        for (int p = 0; p < 9; ++p) {
            const int dh = p / 3, dw = p - dh * 3;
            v4i a[4];
#pragma unroll
            for (int cs = 0; cs < 4; ++cs)
                a[cs] = *(const v4i*)(wp + p * 102400 + cs * 1024);
#pragma unroll
            for (int half = 0; half < 2; ++half) {
                const int prow = wave * 2 + half + dh;
#pragma unroll
                for (int i = 0; i < 4; ++i) {
                    const int col = i * 16 + l15 + dw;
                    const int key = (col >> 1) & 3;
                    v4i bf = *(const v4i*)&B_lds[(prow * 66 + col) * 64 +
                                                 ((quad ^ key) << 4)];
#pragma unroll
                    for (int cs = 0; cs < 4; ++cs)
                        acc[cs][half * 4 + i] =
                            mfma_i8(a[cs], bf, acc[cs][half * 4 + i]);
                }
            }
        }
        __syncthreads();
    }

    // epilogue: y_shift = clip(rint(y*shift)); out = clip(y_shift + b_int8)
    const float shift = *shift_p;
#pragma unroll
    for (int cs = 0; cs < 4; ++cs) {
#pragma unroll
        for (int reg = 0; reg < 4; ++reg) {
            const int co = co0 + cs * 16 + quad * 4 + reg;
            const float bv = bi[co];
#pragma unroll
            for (int half = 0; half < 2; ++half) {
                const int h = h0 + wave * 2 + half;
                float* orow = out + (((size_t)(b * 320 + co) * 64) + h) * 64;
#pragma unroll
                for (int i = 0; i < 4; ++i) {
                    float y  = (float)acc[cs][half * 4 + i][reg];
                    float ys = clampf(rintf(y * shift), -QMAX, QMAX);
                    orow[i * 16 + l15] = clampf(ys + bv, -QMAX, QMAX);
                }
            }
        }
    }
}

extern "C" void kernel_launch(void* const* d_in, const int* in_sizes, int n_in,
                              void* d_out, int out_size, void* d_ws, size_t ws_size,
                              hipStream_t stream) {
    const float* x      = (const float*)d_in[0];
    const float* w      = (const float*)d_in[1];
    const float* bias   = (const float*)d_in[2];
    const float* step_x = (const float*)d_in[3];
    const float* step_w = (const float*)d_in[4];
    const float* step_b = (const float*)d_in[5];
    const float* shift  = (const float*)d_in[6];
    float* out = (float*)d_out;

    char*  xq  = (char*)d_ws;
    char*  wq2 = xq + XQ_BYTES;
    float* bi  = (float*)(wq2 + WQ_BYTES);

    quant_x_kernel<<<dim3(64, 16), 256, 0, stream>>>(x, step_x, xq);
    prep_kernel<<<3926, 256, 0, stream>>>(w, bias, step_w, step_b, step_x, shift,
                                          wq2, xq, bi);
    conv_mfma_kernel<<<dim3(5, 128), 256, 0, stream>>>(xq, wq2, bi, shift, out);
}

// Round 5
// 239.046 us; speedup vs baseline: 2.0825x; 2.0825x over previous
//
#include <hip/hip_runtime.h>

typedef int v4i __attribute__((ext_vector_type(4)));

#define QMAX 127.0f

// ---- workspace layout ----
// xq  : int8 padded, swizzled [16][66][66 px][5 c5][4 slots][16]
//       slot s of (col,c5) holds logical ci-chunk s ^ ((col>>1)&3)
// wq2 : int8 fragment-order [9][5][20cog][64lane][16]
// bi  : float [320]
#define XQ_BYTES 22302720
#define WQ_BYTES 921600

__device__ __forceinline__ float clampf(float v, float lo, float hi) {
    return fminf(fmaxf(v, lo), hi);
}

// Bit-exact fast round(v/step): reciprocal multiply, with exact-division
// fallback only when the quotient is within guard distance of a half-integer
// (reciprocal path error <= ~2e-7*|t|; guard is 1e-5*|t|+1e-5 -> 50x margin).
__device__ __forceinline__ float qround(float v, float step, float inv) {
    float t = v * inv;
    float r = rintf(t);
    float d = fabsf(t - r);
    if (fabsf(d - 0.5f) < fabsf(t) * 1e-5f + 1e-5f)
        r = rintf(v / step);
    return r;
}

__device__ __forceinline__ void gload_lds16(const char* g, char* l) {
    __builtin_amdgcn_global_load_lds(
        (const __attribute__((address_space(1))) void*)g,
        (__attribute__((address_space(3))) void*)l, 16, 0, 0);
}

__device__ __forceinline__ v4i mfma_i8(v4i a, v4i b, v4i c) {
    return __builtin_amdgcn_mfma_i32_16x16x64_i8(a, b, c, 0, 0, 0);
}

// ---------------------------------------------------------------------------
// x (NCHW f32) -> quantize -> xq interior. One block per (h,b): writes the
// full contiguous 20,480B span of row h+1. Guarded-reciprocal quantize.
// ---------------------------------------------------------------------------
__global__ __launch_bounds__(256) void quant_x_kernel(
    const float* __restrict__ x, const float* __restrict__ step_p,
    char* __restrict__ xq)
{
    __shared__ float F[64 * 65];   // [ci_local][w], stride 65 floats
    const int t = threadIdx.x;
    const int h = blockIdx.x;
    const int b = blockIdx.y;
    const float step = *step_p;
    const float inv  = 1.0f / step;
    const int w  = t >> 2;         // output col-1 (0..63)
    const int cg = t & 3;          // logical 16-ci chunk within c5
    v4i vals[5];

    for (int c5 = 0; c5 < 5; ++c5) {
        // phase 1: 64 ci-rows x 64 w; wave-instr = 4 contiguous 256B rows
        {
            const int r = t >> 4, c = (t & 15) * 4;
            const float* src = x + (((size_t)(b * 320 + c5 * 64) * 64 + h) * 64);
#pragma unroll
            for (int i = 0; i < 4; ++i) {
                const int row = r + i * 16;
                *(float4*)&F[row * 65 + c] =
                    *(const float4*)(src + (size_t)row * 4096 + c);
            }
        }
        __syncthreads();
        // phase 2: pack 16 ci bytes for pixel col w+1
        int dws[4];
#pragma unroll
        for (int j = 0; j < 4; ++j) {
            int word = 0;
#pragma unroll
            for (int k = 0; k < 4; ++k) {
                float v = F[(cg * 16 + j * 4 + k) * 65 + w];
                int xi = (int)clampf(qround(v, step, inv), -QMAX, QMAX);
                word |= (xi & 0xFF) << (8 * k);
            }
            dws[j] = word;
        }
        vals[c5] = (v4i){dws[0], dws[1], dws[2], dws[3]};
        __syncthreads();
    }

    // store: full 320B ci-vector of (b, h+1, w+1); swizzled chunk slot
    const int col = w + 1;
    const int key = (col >> 1) & 3;
    char* base = xq + ((size_t)(b * 66 + (h + 1)) * 66 + col) * 320;
#pragma unroll
    for (int c5 = 0; c5 < 5; ++c5)
        *(v4i*)(base + c5 * 64 + (((cg ^ key)) << 4)) = vals[c5];
}

// ---------------------------------------------------------------------------
// Fused prep: [0,3600) wq2 quantize (coalesced writes), [3600,3925) halo zero
// (zeros are swizzle-invariant), [3925] bias constant.
// ---------------------------------------------------------------------------
__global__ __launch_bounds__(256) void prep_kernel(
    const float* __restrict__ w, const float* __restrict__ bias,
    const float* __restrict__ step_w_p, const float* __restrict__ step_b_p,
    const float* __restrict__ step_x_p, const float* __restrict__ shift_p,
    char* __restrict__ wq2, char* __restrict__ xq, float* __restrict__ bi)
{
    const int bid = blockIdx.x;
    if (bid < 3600) {
        const int tid = bid * 256 + threadIdx.x;
        const float step = *step_w_p;
        const float inv  = 1.0f / step;
        const int p    = tid / 102400;
        const int r    = tid - p * 102400;
        const int c5   = r / 20480;
        const int r2   = r - c5 * 20480;
        const int cog  = r2 >> 10;
        const int r3   = r2 & 1023;
        const int lane = r3 >> 4, j = r3 & 15;
        const int co = cog * 16 + (lane & 15);
        const int ci = c5 * 64 + (lane >> 4) * 16 + j;
        float v = w[(size_t)co * 2880 + ci * 9 + p];
        int q = (int)clampf(qround(v, step, inv), -QMAX, QMAX);
        wq2[tid] = (char)q;
    } else if (bid < 3925) {
        int tid = (bid - 3600) * 256 + threadIdx.x;
        if (tid < 83200) {
            int b = tid / 5200;
            int r = tid - b * 5200;
            int px = r / 20;
            int ck = (r - px * 20) * 16;
            int row, col;
            if (px < 66)       { row = 0;  col = px; }
            else if (px < 132) { row = 65; col = px - 66; }
            else { int e = px - 132; row = 1 + (e >> 1); col = (e & 1) * 65; }
            size_t off = ((size_t)(b * 66 + row) * 66 + col) * 320 + ck;
            v4i z = {0, 0, 0, 0};
            *(v4i*)&xq[off] = z;
        }
    } else {
        const float step_b = *step_b_p;
        const float xs = 1.0f / *step_x_p;
        const float ws = 1.0f / *step_w_p;
        const float shift = *shift_p;
#pragma unroll
        for (int co = threadIdx.x; co < 320; co += 256) {
            float b_deq = clampf(rintf(bias[co] / step_b), -QMAX, QMAX) * step_b;
            float v = ((b_deq * shift) * xs) * ws;
            bi[co] = clampf(rintf(v), -QMAX, QMAX);
        }
    }
}

// ---------------------------------------------------------------------------
// Implicit-GEMM conv, v_mfma_i32_16x16x64_i8.
// Block = 2 waves (128 thr), wave tile 64co x 128px (2 output rows) ->
// block = 4 output rows, 6 padded rows, B_lds = 25,344 B.
// B staged by global_load_lds DMA (xq pre-swizzled); A read directly from
// L2-hot wq2 (1KB coalesced per wave-instr). launch_bounds(128,2): 256
// unified regs/wave (acc 128 AGPR + ~100 VGPR fits; r4's (256,3) spilled).
// Occupancy: 8 waves/CU = 4 independent barrier domains per CU.
// ---------------------------------------------------------------------------
__global__ __launch_bounds__(128, 2) void conv_mfma_kernel(
    const char* __restrict__ xq, const char* __restrict__ wq2,
    const float* __restrict__ bi, const float* __restrict__ shift_p,
    float* __restrict__ out)
{
    __shared__ __attribute__((aligned(16))) char B_lds[25344]; // 6 rows x 66 x 64

    const int t   = threadIdx.x;
    const int bx  = blockIdx.x;          // co tile 0..4
    const int co0 = bx * 64;
    const int ptile = blockIdx.y;        // 0..255
    const int b  = ptile >> 4;
    const int h0 = (ptile & 15) * 4;

    const int wave = t >> 6, lane = t & 63;
    const int quad = lane >> 4, l15 = lane & 15;

    const char* xbase = xq + ((size_t)(b * 66 + h0) * 66) * 320;

    v4i acc[4][8] = {};

    for (int c5 = 0; c5 < 5; ++c5) {
        const int ci0 = c5 * 64;
        const char* wp = wq2 + (c5 * 20 + bx * 4) * 1024 + lane * 16;

        // --- stage B: 1584 16B chunks via LDS-DMA (global already swizzled)
        for (int c = t; c < 1584; c += 128) {
            const char* g = xbase + (c >> 2) * 320 + ci0 + ((c & 3) << 4);
            gload_lds16(g, &B_lds[(c - lane) * 16]);
        }
        __syncthreads();

#pragma unroll
        for (int p = 0; p < 9; ++p) {
            const int dh = p / 3, dw = p - dh * 3;
            v4i a[4];
#pragma unroll
            for (int cs = 0; cs < 4; ++cs)
                a[cs] = *(const v4i*)(wp + p * 102400 + cs * 1024);
#pragma unroll
            for (int half = 0; half < 2; ++half) {
                const int prow = wave * 2 + half + dh;
#pragma unroll
                for (int i = 0; i < 4; ++i) {
                    const int col = i * 16 + l15 + dw;
                    const int key = (col >> 1) & 3;
                    v4i bf = *(const v4i*)&B_lds[(prow * 66 + col) * 64 +
                                                 ((quad ^ key) << 4)];
#pragma unroll
                    for (int cs = 0; cs < 4; ++cs)
                        acc[cs][half * 4 + i] =
                            mfma_i8(a[cs], bf, acc[cs][half * 4 + i]);
                }
            }
        }
        __syncthreads();
    }

    // epilogue: y_shift = clip(rint(y*shift)); out = clip(y_shift + b_int8)
    const float shift = *shift_p;
#pragma unroll
    for (int cs = 0; cs < 4; ++cs) {
#pragma unroll
        for (int reg = 0; reg < 4; ++reg) {
            const int co = co0 + cs * 16 + quad * 4 + reg;
            const float bv = bi[co];
#pragma unroll
            for (int half = 0; half < 2; ++half) {
                const int h = h0 + wave * 2 + half;
                float* orow = out + (((size_t)(b * 320 + co) * 64) + h) * 64;
#pragma unroll
                for (int i = 0; i < 4; ++i) {
                    float y  = (float)acc[cs][half * 4 + i][reg];
                    float ys = clampf(rintf(y * shift), -QMAX, QMAX);
                    orow[i * 16 + l15] = clampf(ys + bv, -QMAX, QMAX);
                }
            }
        }
    }
}

extern "C" void kernel_launch(void* const* d_in, const int* in_sizes, int n_in,
                              void* d_out, int out_size, void* d_ws, size_t ws_size,
                              hipStream_t stream) {
    const float* x      = (const float*)d_in[0];
    const float* w      = (const float*)d_in[1];
    const float* bias   = (const float*)d_in[2];
    const float* step_x = (const float*)d_in[3];
    const float* step_w = (const float*)d_in[4];
    const float* step_b = (const float*)d_in[5];
    const float* shift  = (const float*)d_in[6];
    float* out = (float*)d_out;

    char*  xq  = (char*)d_ws;
    char*  wq2 = xq + XQ_BYTES;
    float* bi  = (float*)(wq2 + WQ_BYTES);

    quant_x_kernel<<<dim3(64, 16), 256, 0, stream>>>(x, step_x, xq);
    prep_kernel<<<3926, 256, 0, stream>>>(w, bias, step_w, step_b, step_x, shift,
                                          wq2, xq, bi);
    conv_mfma_kernel<<<dim3(5, 256), 128, 0, stream>>>(xq, wq2, bi, shift, out);
}

// Round 6
// 223.805 us; speedup vs baseline: 2.2243x; 1.0681x over previous
//
#include <hip/hip_runtime.h>

typedef int v4i __attribute__((ext_vector_type(4)));

#define QMAX 127.0f

// ---- workspace layout ----
// xq  : int8 padded, swizzled [16][66][66 px][5 c5][4 slots][16]
//       slot s of (col,c5) holds logical ci-chunk s ^ ((col>>1)&3)
// wq2 : int8 fragment-order [9][5][20cog][64lane][16]
// bi  : float [320]
#define XQ_BYTES 22302720
#define WQ_BYTES 921600

__device__ __forceinline__ float clampf(float v, float lo, float hi) {
    return fminf(fmaxf(v, lo), hi);
}

// Bit-exact fast round(v/step): reciprocal multiply, exact-division fallback
// only near half-integer boundaries (trigger ~7e-4; 50x error margin).
__device__ __forceinline__ float qround(float v, float step, float inv) {
    float t = v * inv;
    float r = rintf(t);
    float d = fabsf(t - r);
    if (fabsf(d - 0.5f) < fabsf(t) * 1e-5f + 1e-5f)
        r = rintf(v / step);
    return r;
}

__device__ __forceinline__ void gload_lds16(const char* g, char* l) {
    __builtin_amdgcn_global_load_lds(
        (const __attribute__((address_space(1))) void*)g,
        (__attribute__((address_space(3))) void*)l, 16, 0, 0);
}

__device__ __forceinline__ v4i mfma_i8(v4i a, v4i b, v4i c) {
    return __builtin_amdgcn_mfma_i32_16x16x64_i8(a, b, c, 0, 0, 0);
}

// ---------------------------------------------------------------------------
// x (NCHW f32) -> quantize -> xq interior. One block per (h,b): writes the
// full contiguous 20,480B span of row h+1.
// ---------------------------------------------------------------------------
__global__ __launch_bounds__(256) void quant_x_kernel(
    const float* __restrict__ x, const float* __restrict__ step_p,
    char* __restrict__ xq)
{
    __shared__ float F[64 * 65];   // [ci_local][w], stride 65 floats
    const int t = threadIdx.x;
    const int h = blockIdx.x;
    const int b = blockIdx.y;
    const float step = *step_p;
    const float inv  = 1.0f / step;
    const int w  = t >> 2;         // output col-1 (0..63)
    const int cg = t & 3;          // logical 16-ci chunk within c5
    v4i vals[5];

    for (int c5 = 0; c5 < 5; ++c5) {
        {
            const int r = t >> 4, c = (t & 15) * 4;
            const float* src = x + (((size_t)(b * 320 + c5 * 64) * 64 + h) * 64);
#pragma unroll
            for (int i = 0; i < 4; ++i) {
                const int row = r + i * 16;
                *(float4*)&F[row * 65 + c] =
                    *(const float4*)(src + (size_t)row * 4096 + c);
            }
        }
        __syncthreads();
        int dws[4];
#pragma unroll
        for (int j = 0; j < 4; ++j) {
            int word = 0;
#pragma unroll
            for (int k = 0; k < 4; ++k) {
                float v = F[(cg * 16 + j * 4 + k) * 65 + w];
                int xi = (int)clampf(qround(v, step, inv), -QMAX, QMAX);
                word |= (xi & 0xFF) << (8 * k);
            }
            dws[j] = word;
        }
        vals[c5] = (v4i){dws[0], dws[1], dws[2], dws[3]};
        __syncthreads();
    }

    const int col = w + 1;
    const int key = (col >> 1) & 3;
    char* base = xq + ((size_t)(b * 66 + (h + 1)) * 66 + col) * 320;
#pragma unroll
    for (int c5 = 0; c5 < 5; ++c5)
        *(v4i*)(base + c5 * 64 + (((cg ^ key)) << 4)) = vals[c5];
}

// ---------------------------------------------------------------------------
// Fused prep: [0,3600) wq2 quantize, [3600,3925) halo zero, [3925] bias.
// ---------------------------------------------------------------------------
__global__ __launch_bounds__(256) void prep_kernel(
    const float* __restrict__ w, const float* __restrict__ bias,
    const float* __restrict__ step_w_p, const float* __restrict__ step_b_p,
    const float* __restrict__ step_x_p, const float* __restrict__ shift_p,
    char* __restrict__ wq2, char* __restrict__ xq, float* __restrict__ bi)
{
    const int bid = blockIdx.x;
    if (bid < 3600) {
        const int tid = bid * 256 + threadIdx.x;
        const float step = *step_w_p;
        const float inv  = 1.0f / step;
        const int p    = tid / 102400;
        const int r    = tid - p * 102400;
        const int c5   = r / 20480;
        const int r2   = r - c5 * 20480;
        const int cog  = r2 >> 10;
        const int r3   = r2 & 1023;
        const int lane = r3 >> 4, j = r3 & 15;
        const int co = cog * 16 + (lane & 15);
        const int ci = c5 * 64 + (lane >> 4) * 16 + j;
        float v = w[(size_t)co * 2880 + ci * 9 + p];
        int q = (int)clampf(qround(v, step, inv), -QMAX, QMAX);
        wq2[tid] = (char)q;
    } else if (bid < 3925) {
        int tid = (bid - 3600) * 256 + threadIdx.x;
        if (tid < 83200) {
            int b = tid / 5200;
            int r = tid - b * 5200;
            int px = r / 20;
            int ck = (r - px * 20) * 16;
            int row, col;
            if (px < 66)       { row = 0;  col = px; }
            else if (px < 132) { row = 65; col = px - 66; }
            else { int e = px - 132; row = 1 + (e >> 1); col = (e & 1) * 65; }
            size_t off = ((size_t)(b * 66 + row) * 66 + col) * 320 + ck;
            v4i z = {0, 0, 0, 0};
            *(v4i*)&xq[off] = z;
        }
    } else {
        const float step_b = *step_b_p;
        const float xs = 1.0f / *step_x_p;
        const float ws = 1.0f / *step_w_p;
        const float shift = *shift_p;
#pragma unroll
        for (int co = threadIdx.x; co < 320; co += 256) {
            float b_deq = clampf(rintf(bias[co] / step_b), -QMAX, QMAX) * step_b;
            float v = ((b_deq * shift) * xs) * ws;
            bi[co] = clampf(rintf(v), -QMAX, QMAX);
        }
    }
}

// ---------------------------------------------------------------------------
// Implicit-GEMM conv, v_mfma_i32_16x16x64_i8.
// Block = 4 waves (256 thr); wave tile 64co x 64px (1 output row) -> acc 64
// AGPR, ~140 regs/wave -> 3 waves/SIMD (launch_bounds(256,3)).
// Double-buffered B (2 x 25,344 B): DMA for c5+1 issued BEFORE computing c5,
// so the barrier's vmcnt drain overlaps ~6000 cyc of MFMA. One barrier/c5.
// A read directly from L2-hot wq2 (1KB coalesced per wave-instr).
// ---------------------------------------------------------------------------
__global__ __launch_bounds__(256, 3) void conv_mfma_kernel(
    const char* __restrict__ xq, const char* __restrict__ wq2,
    const float* __restrict__ bi, const float* __restrict__ shift_p,
    float* __restrict__ out)
{
    __shared__ __attribute__((aligned(16))) char B_lds[2][25344]; // 6 rows x 66 x 64

    const int t   = threadIdx.x;
    const int bx  = blockIdx.x;          // co tile 0..4
    const int co0 = bx * 64;
    const int ptile = blockIdx.y;        // 0..255
    const int b  = ptile >> 4;
    const int h0 = (ptile & 15) * 4;

    const int wave = t >> 6, lane = t & 63;
    const int quad = lane >> 4, l15 = lane & 15;

    const char* xbase = xq + ((size_t)(b * 66 + h0) * 66) * 320;

    v4i acc[4][4] = {};

    // prologue: stage c5=0 into buffer 0
    for (int c = t; c < 1584; c += 256) {
        const char* g = xbase + (c >> 2) * 320 + ((c & 3) << 4);
        gload_lds16(g, &B_lds[0][(c - lane) * 16]);
    }
    __syncthreads();

    for (int c5 = 0; c5 < 5; ++c5) {
        // issue next stage's DMA first (lands in the other buffer; drained by
        // the barrier AFTER this c5's compute -> fully overlapped)
        if (c5 < 4) {
            const int ci0 = (c5 + 1) * 64;
            char* dst = B_lds[(c5 + 1) & 1];
            for (int c = t; c < 1584; c += 256) {
                const char* g = xbase + (c >> 2) * 320 + ci0 + ((c & 3) << 4);
                gload_lds16(g, &dst[(c - lane) * 16]);
            }
        }

        const char* Bc = B_lds[c5 & 1];
        const char* wp = wq2 + (c5 * 20 + bx * 4) * 1024 + lane * 16;

#pragma unroll
        for (int p = 0; p < 9; ++p) {
            const int dh = p / 3, dw = p - dh * 3;
            v4i a[4];
#pragma unroll
            for (int cs = 0; cs < 4; ++cs)
                a[cs] = *(const v4i*)(wp + p * 102400 + cs * 1024);
            const int prow = wave + dh;
#pragma unroll
            for (int i = 0; i < 4; ++i) {
                const int col = i * 16 + l15 + dw;
                const int key = (col >> 1) & 3;
                v4i bf = *(const v4i*)&Bc[(prow * 66 + col) * 64 +
                                          ((quad ^ key) << 4)];
#pragma unroll
                for (int cs = 0; cs < 4; ++cs)
                    acc[cs][i] = mfma_i8(a[cs], bf, acc[cs][i]);
            }
        }
        __syncthreads();
    }

    // epilogue: y_shift = clip(rint(y*shift)); out = clip(y_shift + b_int8)
    const float shift = *shift_p;
    const int h = h0 + wave;
#pragma unroll
    for (int cs = 0; cs < 4; ++cs) {
#pragma unroll
        for (int reg = 0; reg < 4; ++reg) {
            const int co = co0 + cs * 16 + quad * 4 + reg;
            const float bv = bi[co];
            float* orow = out + (((size_t)(b * 320 + co) * 64) + h) * 64;
#pragma unroll
            for (int i = 0; i < 4; ++i) {
                float y  = (float)acc[cs][i][reg];
                float ys = clampf(rintf(y * shift), -QMAX, QMAX);
                orow[i * 16 + l15] = clampf(ys + bv, -QMAX, QMAX);
            }
        }
    }
}

extern "C" void kernel_launch(void* const* d_in, const int* in_sizes, int n_in,
                              void* d_out, int out_size, void* d_ws, size_t ws_size,
                              hipStream_t stream) {
    const float* x      = (const float*)d_in[0];
    const float* w      = (const float*)d_in[1];
    const float* bias   = (const float*)d_in[2];
    const float* step_x = (const float*)d_in[3];
    const float* step_w = (const float*)d_in[4];
    const float* step_b = (const float*)d_in[5];
    const float* shift  = (const float*)d_in[6];
    float* out = (float*)d_out;

    char*  xq  = (char*)d_ws;
    char*  wq2 = xq + XQ_BYTES;
    float* bi  = (float*)(wq2 + WQ_BYTES);

    quant_x_kernel<<<dim3(64, 16), 256, 0, stream>>>(x, step_x, xq);
    prep_kernel<<<3926, 256, 0, stream>>>(w, bias, step_w, step_b, step_x, shift,
                                          wq2, xq, bi);
    conv_mfma_kernel<<<dim3(5, 256), 256, 0, stream>>>(xq, wq2, bi, shift, out);
}